// Round 1
// baseline (2849.363 us; speedup 1.0000x reference)
//
#include <hip/hip_runtime.h>
#include <hip/hip_bf16.h>

#define N_NODES 20000
#define E_EDGES 320000
#define F_INN   64
#define HID     128
#define HEADS   2
#define HC      (HEADS * HID)   // 256
#define G_GR    64
#define MIDD    32
#define EPSV    1e-5f

#define CDIV(a, b) (((a) + (b) - 1) / (b))

__device__ inline void atomicMaxFloat(float* addr, float val) {
    unsigned int* ua = (unsigned int*)addr;
    unsigned int old = __float_as_uint(*addr);
    while (!(__uint_as_float(old) >= val)) {
        unsigned int assumed = old;
        old = atomicCAS(ua, assumed, __float_as_uint(val));
        if (old == assumed) break;
    }
}

// ---------- generic utility kernels ----------
__global__ void k_fill(float* __restrict__ p, float v, int n) {
    int i = blockIdx.x * blockDim.x + threadIdx.x;
    if (i < n) p[i] = v;
}

__global__ void k_copy(const float* __restrict__ src, float* __restrict__ dst, int n) {
    int i = blockIdx.x * blockDim.x + threadIdx.x;
    if (i < n) dst[i] = src[i];
}

// ---------- GANConv aggregation: z[row] += x[col] ----------
__global__ void k_edge_agg(const float* __restrict__ x, const int* __restrict__ row,
                           const int* __restrict__ col, float* __restrict__ z, int C) {
    int idx = blockIdx.x * blockDim.x + threadIdx.x;
    if (idx >= E_EDGES * C) return;
    int e = idx / C;
    int c = idx - e * C;
    atomicAdd(&z[(size_t)row[e] * C + c], x[(size_t)col[e] * C + c]);
}

// ---------- tiled fp32 GEMM: C = A[M,K] @ W[K,NC] + bias, optional relu ----------
__global__ __launch_bounds__(256) void k_gemm_bias(const float* __restrict__ A,
                                                   const float* __restrict__ W,
                                                   const float* __restrict__ bias,
                                                   float* __restrict__ Cout,
                                                   int M, int K, int NC, int relu) {
    __shared__ float As[16][17];
    __shared__ float Ws[16][17];
    int tx = threadIdx.x, ty = threadIdx.y;
    int col  = blockIdx.x * 16 + tx;
    int rowi = blockIdx.y * 16 + ty;
    float acc = 0.f;
    for (int k0 = 0; k0 < K; k0 += 16) {
        As[ty][tx] = (rowi < M) ? A[(size_t)rowi * K + k0 + tx] : 0.f;
        Ws[ty][tx] = (col < NC) ? W[(size_t)(k0 + ty) * NC + col] : 0.f;
        __syncthreads();
#pragma unroll
        for (int kk = 0; kk < 16; kk++) acc += As[ty][kk] * Ws[kk][tx];
        __syncthreads();
    }
    if (rowi < M && col < NC) {
        float v = acc + bias[col];
        if (relu) v = fmaxf(v, 0.f);
        Cout[(size_t)rowi * NC + col] = v;
    }
}

// ---------- batch norm (training mode) ----------
__global__ void k_bn_stats(const float* __restrict__ X, int M, int C,
                           float* __restrict__ mean, float* __restrict__ istd) {
    int j = blockIdx.x;  // one block per column
    float s = 0.f, s2 = 0.f;
    for (int i = threadIdx.x; i < M; i += blockDim.x) {
        float v = X[(size_t)i * C + j];
        s += v; s2 += v * v;
    }
    __shared__ float sh[256], sh2[256];
    sh[threadIdx.x] = s; sh2[threadIdx.x] = s2;
    __syncthreads();
    for (int o = 128; o > 0; o >>= 1) {
        if (threadIdx.x < o) { sh[threadIdx.x] += sh[threadIdx.x + o]; sh2[threadIdx.x] += sh2[threadIdx.x + o]; }
        __syncthreads();
    }
    if (threadIdx.x == 0) {
        float m = sh[0] / M;
        float var = sh2[0] / M - m * m;
        mean[j] = m;
        istd[j] = rsqrtf(var + EPSV);
    }
}

__global__ void k_bn_apply(float* __restrict__ X, int M, int C,
                           const float* __restrict__ mean, const float* __restrict__ istd,
                           const float* __restrict__ g, const float* __restrict__ b, int relu) {
    int idx = blockIdx.x * blockDim.x + threadIdx.x;
    if (idx >= M * C) return;
    int j = idx % C;
    float v = (X[idx] - mean[j]) * istd[j] * g[j] + b[j];
    if (relu) v = fmaxf(v, 0.f);
    X[idx] = v;
}

// ---------- ATTConv (GATv2-style) ----------
// logit[e,h] = sum_c att[h,c] * leaky_relu(xl[src,h,c] + xr[dst,h,c], 0.2); also segment-max into lmax
__global__ void k_att_logit(const float* __restrict__ xl, const float* __restrict__ xr,
                            const int* __restrict__ src, const int* __restrict__ dst,
                            const float* __restrict__ att,
                            float* __restrict__ logit, float* __restrict__ lmax) {
    int idx = blockIdx.x * blockDim.x + threadIdx.x;  // e*HEADS + h
    if (idx >= E_EDGES * HEADS) return;
    int e = idx >> 1;
    int h = idx & 1;
    const float* pl = xl + (size_t)src[e] * HC + h * HID;
    const float* pr = xr + (size_t)dst[e] * HC + h * HID;
    const float* pa = att + h * HID;
    float acc = 0.f;
#pragma unroll 4
    for (int c = 0; c < HID; c++) {
        float v = pl[c] + pr[c];
        v = (v > 0.f) ? v : 0.2f * v;
        acc += pa[c] * v;
    }
    logit[idx] = acc;
    atomicMaxFloat(&lmax[(size_t)dst[e] * HEADS + h], acc);
}

// w = exp(logit - lmax[dst]); denom[dst] += w   (w written in-place over logit)
__global__ void k_att_expsum(float* __restrict__ logit, const int* __restrict__ dst,
                             const float* __restrict__ lmax, float* __restrict__ denom) {
    int idx = blockIdx.x * blockDim.x + threadIdx.x;
    if (idx >= E_EDGES * HEADS) return;
    int e = idx >> 1;
    int h = idx & 1;
    float w = expf(logit[idx] - lmax[(size_t)dst[e] * HEADS + h]);
    logit[idx] = w;
    atomicAdd(&denom[(size_t)dst[e] * HEADS + h], w);
}

// alpha = w / (denom[dst] + 1e-16); optionally also emit alpha to output buffer
__global__ void k_att_alpha(float* __restrict__ w, const int* __restrict__ dst,
                            const float* __restrict__ denom, float* __restrict__ alpha_out) {
    int idx = blockIdx.x * blockDim.x + threadIdx.x;
    if (idx >= E_EDGES * HEADS) return;
    int e = idx >> 1;
    int h = idx & 1;
    float a = w[idx] / (denom[(size_t)dst[e] * HEADS + h] + 1e-16f);
    w[idx] = a;
    if (alpha_out) alpha_out[idx] = a;
}

// out[dst,h,c] += alpha[e,h] * xl[src,h,c]
__global__ void k_att_accum(const float* __restrict__ xl, const float* __restrict__ alpha,
                            const int* __restrict__ src, const int* __restrict__ dst,
                            float* __restrict__ out) {
    int idx = blockIdx.x * blockDim.x + threadIdx.x;  // e*HC + hc
    if (idx >= E_EDGES * HC) return;
    int e = idx / HC;
    int hc = idx - e * HC;
    int h = hc >> 7;  // HID=128
    float a = alpha[e * HEADS + h];
    atomicAdd(&out[(size_t)dst[e] * HC + hc], a * xl[(size_t)src[e] * HC + hc]);
}

// att1 finalize: emb = relu(out + bias)  (concat=True, [N, HC])
__global__ void k_att1_final(float* __restrict__ out, const float* __restrict__ bias) {
    int idx = blockIdx.x * blockDim.x + threadIdx.x;
    if (idx >= N_NODES * HC) return;
    float v = out[idx] + bias[idx % HC];
    out[idx] = fmaxf(v, 0.f);
}

// att2 finalize: atten_out = relu(mean_h(out) + bias)  ([N, HID])
__global__ void k_att2_final(const float* __restrict__ out, const float* __restrict__ bias,
                             float* __restrict__ atten_out) {
    int idx = blockIdx.x * blockDim.x + threadIdx.x;
    if (idx >= N_NODES * HID) return;
    int n = idx / HID;
    int c = idx - n * HID;
    float v = 0.5f * (out[(size_t)n * HC + c] + out[(size_t)n * HC + HID + c]) + bias[c];
    atten_out[idx] = fmaxf(v, 0.f);
}

// ---------- pooling: pool[batch[n], c] += X[n, c] ----------
__global__ void k_pool(const float* __restrict__ X, const int* __restrict__ batch,
                       float* __restrict__ pool, int C) {
    int idx = blockIdx.x * blockDim.x + threadIdx.x;
    if (idx >= N_NODES * C) return;
    int n = idx / C;
    int c = idx - n * C;
    atomicAdd(&pool[(size_t)batch[n] * C + c], X[idx]);
}

// ---------- final prediction head ----------
__global__ void k_head(const float* __restrict__ pool0, const float* __restrict__ poolL,
                       const float* __restrict__ p0w, const float* __restrict__ p0b,
                       const float* __restrict__ pLw, const float* __restrict__ pLb,
                       const float* __restrict__ ow, const float* __restrict__ ob,
                       float* __restrict__ outputs) {
    int g = blockIdx.x;
    int m = threadIdx.x;  // 64 threads; first 32 compute MID outputs
    __shared__ float sh[MIDD];
    if (m < MIDD) {
        float s = p0b[m] + pLb[m];
        for (int k = 0; k < F_INN; k++) s += pool0[g * F_INN + k] * p0w[k * MIDD + m];
        for (int k = 0; k < HID; k++)  s += poolL[g * HID + k] * pLw[k * MIDD + m];
        sh[m] = fmaxf(s, 0.f);
    }
    __syncthreads();
    if (m == 0) {
        float s = ob[0];
        for (int k = 0; k < MIDD; k++) s += sh[k] * ow[k];
        outputs[g] = s;
    }
}

extern "C" void kernel_launch(void* const* d_in, const int* in_sizes, int n_in,
                              void* d_out, int out_size, void* d_ws, size_t ws_size,
                              hipStream_t stream) {
    // ---- inputs ----
    const float* x      = (const float*)d_in[0];
    const int*   ei     = (const int*)d_in[1];   // [2,E]: row=ei, col=ei+E
    const int*   aei    = (const int*)d_in[2];
    const int*   batch  = (const int*)d_in[3];
    const float* g0_w1  = (const float*)d_in[4];
    const float* g0_b1  = (const float*)d_in[5];
    const float* g0_bng = (const float*)d_in[6];
    const float* g0_bnb = (const float*)d_in[7];
    const float* g0_w2  = (const float*)d_in[8];
    const float* g0_b2  = (const float*)d_in[9];
    const float* g1_w1  = (const float*)d_in[10];
    const float* g1_b1  = (const float*)d_in[11];
    const float* g1_bng = (const float*)d_in[12];
    const float* g1_bnb = (const float*)d_in[13];
    const float* g1_w2  = (const float*)d_in[14];
    const float* g1_b2  = (const float*)d_in[15];
    const float* bn0_g  = (const float*)d_in[16];
    const float* bn0_b  = (const float*)d_in[17];
    const float* bn1_g  = (const float*)d_in[18];
    const float* bn1_b  = (const float*)d_in[19];
    const float* a1_wl  = (const float*)d_in[20];
    const float* a1_bl  = (const float*)d_in[21];
    const float* a1_wr  = (const float*)d_in[22];
    const float* a1_br  = (const float*)d_in[23];
    const float* a1_att = (const float*)d_in[24];
    const float* a1_bias= (const float*)d_in[25];
    const float* a2_wl  = (const float*)d_in[26];
    const float* a2_bl  = (const float*)d_in[27];
    const float* a2_wr  = (const float*)d_in[28];
    const float* a2_br  = (const float*)d_in[29];
    const float* a2_att = (const float*)d_in[30];
    const float* a2_bias= (const float*)d_in[31];
    const float* p0w    = (const float*)d_in[32];
    const float* p0b    = (const float*)d_in[33];
    const float* pLw    = (const float*)d_in[34];
    const float* pLb    = (const float*)d_in[35];
    const float* ow     = (const float*)d_in[36];
    const float* ob     = (const float*)d_in[37];

    // ---- outputs (flat concat in return order) ----
    float* out_head  = (float*)d_out;                     // [G,1] = 64
    float* atten_out = out_head + G_GR;                   // [N,HID]
    float* alpha_out = atten_out + (size_t)N_NODES * HID; // [E,HEADS]

    // ---- workspace layout ----
    float* ws = (float*)d_ws;
    const size_t NB = (size_t)N_NODES * HC;  // N*256
    float* A     = ws;
    float* B     = A + NB;
    float* Cb    = B + NB;
    float* D     = Cb + NB;
    float* logit = D + NB;                       // E*HEADS
    float* lmax  = logit + (size_t)E_EDGES * HEADS;  // N*HEADS
    float* denom = lmax + (size_t)N_NODES * HEADS;   // N*HEADS
    float* mean  = denom + (size_t)N_NODES * HEADS;  // 256
    float* istd  = mean + 256;                       // 256
    float* pool0 = istd + 256;                       // G*F_IN
    float* poolL = pool0 + G_GR * F_INN;             // G*HID

    const int* e_row = ei;          // gan: agg dst / att1: src
    const int* e_col = ei + E_EDGES;
    const int* a_src = aei;
    const int* a_dst = aei + E_EDGES;

    const int TB = 256;
    dim3 blk16(16, 16);

#define GRID1(n) dim3(CDIV((n), TB))

    // ===== GANConv 0: z = x + segsum(x[col] -> row); mlp2 =====
    hipLaunchKernelGGL(k_copy, GRID1(N_NODES * F_INN), dim3(TB), 0, stream, x, A, N_NODES * F_INN);
    hipLaunchKernelGGL(k_edge_agg, GRID1(E_EDGES * F_INN), dim3(TB), 0, stream, x, e_row, e_col, A, F_INN);
    hipLaunchKernelGGL(k_gemm_bias, dim3(HID / 16, CDIV(N_NODES, 16)), blk16, 0, stream,
                       A, g0_w1, g0_b1, B, N_NODES, F_INN, HID, 0);
    hipLaunchKernelGGL(k_bn_stats, dim3(HID), dim3(256), 0, stream, B, N_NODES, HID, mean, istd);
    hipLaunchKernelGGL(k_bn_apply, GRID1(N_NODES * HID), dim3(TB), 0, stream, B, N_NODES, HID, mean, istd, g0_bng, g0_bnb, 1);
    hipLaunchKernelGGL(k_gemm_bias, dim3(HID / 16, CDIV(N_NODES, 16)), blk16, 0, stream,
                       B, g0_w2, g0_b2, Cb, N_NODES, HID, HID, 0);
    hipLaunchKernelGGL(k_bn_stats, dim3(HID), dim3(256), 0, stream, Cb, N_NODES, HID, mean, istd);
    hipLaunchKernelGGL(k_bn_apply, GRID1(N_NODES * HID), dim3(TB), 0, stream, Cb, N_NODES, HID, mean, istd, bn0_g, bn0_b, 1);
    // h1 in Cb [N,HID]

    // ===== GANConv 1 =====
    hipLaunchKernelGGL(k_copy, GRID1(N_NODES * HID), dim3(TB), 0, stream, Cb, A, N_NODES * HID);
    hipLaunchKernelGGL(k_edge_agg, GRID1(E_EDGES * HID), dim3(TB), 0, stream, Cb, e_row, e_col, A, HID);
    hipLaunchKernelGGL(k_gemm_bias, dim3(HID / 16, CDIV(N_NODES, 16)), blk16, 0, stream,
                       A, g1_w1, g1_b1, B, N_NODES, HID, HID, 0);
    hipLaunchKernelGGL(k_bn_stats, dim3(HID), dim3(256), 0, stream, B, N_NODES, HID, mean, istd);
    hipLaunchKernelGGL(k_bn_apply, GRID1(N_NODES * HID), dim3(TB), 0, stream, B, N_NODES, HID, mean, istd, g1_bng, g1_bnb, 1);
    hipLaunchKernelGGL(k_gemm_bias, dim3(HID / 16, CDIV(N_NODES, 16)), blk16, 0, stream,
                       B, g1_w2, g1_b2, A, N_NODES, HID, HID, 0);
    hipLaunchKernelGGL(k_bn_stats, dim3(HID), dim3(256), 0, stream, A, N_NODES, HID, mean, istd);
    hipLaunchKernelGGL(k_bn_apply, GRID1(N_NODES * HID), dim3(TB), 0, stream, A, N_NODES, HID, mean, istd, bn1_g, bn1_b, 1);
    // h2 in A [N,HID]

    // ===== ATTConv 1 (edge_index, concat=True) =====
    hipLaunchKernelGGL(k_gemm_bias, dim3(HC / 16, CDIV(N_NODES, 16)), blk16, 0, stream,
                       A, a1_wl, a1_bl, B, N_NODES, HID, HC, 0);   // xl -> B
    hipLaunchKernelGGL(k_gemm_bias, dim3(HC / 16, CDIV(N_NODES, 16)), blk16, 0, stream,
                       A, a1_wr, a1_br, Cb, N_NODES, HID, HC, 0);  // xr -> Cb
    hipLaunchKernelGGL(k_fill, GRID1(N_NODES * HEADS), dim3(TB), 0, stream, lmax, -INFINITY, N_NODES * HEADS);
    hipMemsetAsync(denom, 0, (size_t)N_NODES * HEADS * sizeof(float), stream);
    hipMemsetAsync(D, 0, NB * sizeof(float), stream);
    hipLaunchKernelGGL(k_att_logit, GRID1(E_EDGES * HEADS), dim3(TB), 0, stream, B, Cb, e_row, e_col, a1_att, logit, lmax);
    hipLaunchKernelGGL(k_att_expsum, GRID1(E_EDGES * HEADS), dim3(TB), 0, stream, logit, e_col, lmax, denom);
    hipLaunchKernelGGL(k_att_alpha, GRID1(E_EDGES * HEADS), dim3(TB), 0, stream, logit, e_col, denom, (float*)nullptr);
    hipLaunchKernelGGL(k_att_accum, GRID1(E_EDGES * HC), dim3(TB), 0, stream, B, logit, e_row, e_col, D);
    hipLaunchKernelGGL(k_att1_final, GRID1(N_NODES * HC), dim3(TB), 0, stream, D, a1_bias);
    // emb in D [N,HC]

    // ===== ATTConv 2 (atten_edge_index, concat=False) =====
    hipLaunchKernelGGL(k_gemm_bias, dim3(HC / 16, CDIV(N_NODES, 16)), blk16, 0, stream,
                       D, a2_wl, a2_bl, B, N_NODES, HC, HC, 0);    // xl -> B
    hipLaunchKernelGGL(k_gemm_bias, dim3(HC / 16, CDIV(N_NODES, 16)), blk16, 0, stream,
                       D, a2_wr, a2_br, Cb, N_NODES, HC, HC, 0);   // xr -> Cb
    hipLaunchKernelGGL(k_fill, GRID1(N_NODES * HEADS), dim3(TB), 0, stream, lmax, -INFINITY, N_NODES * HEADS);
    hipMemsetAsync(denom, 0, (size_t)N_NODES * HEADS * sizeof(float), stream);
    hipMemsetAsync(A, 0, NB * sizeof(float), stream);
    hipLaunchKernelGGL(k_att_logit, GRID1(E_EDGES * HEADS), dim3(TB), 0, stream, B, Cb, a_src, a_dst, a2_att, logit, lmax);
    hipLaunchKernelGGL(k_att_expsum, GRID1(E_EDGES * HEADS), dim3(TB), 0, stream, logit, a_dst, lmax, denom);
    hipLaunchKernelGGL(k_att_alpha, GRID1(E_EDGES * HEADS), dim3(TB), 0, stream, logit, a_dst, denom, alpha_out);
    hipLaunchKernelGGL(k_att_accum, GRID1(E_EDGES * HC), dim3(TB), 0, stream, B, logit, a_src, a_dst, A);
    hipLaunchKernelGGL(k_att2_final, GRID1(N_NODES * HID), dim3(TB), 0, stream, A, a2_bias, atten_out);

    // ===== pooling + head =====
    hipMemsetAsync(pool0, 0, (size_t)G_GR * F_INN * sizeof(float), stream);
    hipMemsetAsync(poolL, 0, (size_t)G_GR * HID * sizeof(float), stream);
    hipLaunchKernelGGL(k_pool, GRID1(N_NODES * F_INN), dim3(TB), 0, stream, x, batch, pool0, F_INN);
    hipLaunchKernelGGL(k_pool, GRID1(N_NODES * HID), dim3(TB), 0, stream, atten_out, batch, poolL, HID);
    hipLaunchKernelGGL(k_head, dim3(G_GR), dim3(64), 0, stream, pool0, poolL, p0w, p0b, pLw, pLb, ow, ob, out_head);
}